// Round 1
// baseline (336.456 us; speedup 1.0000x reference)
//
#include <hip/hip_runtime.h>
#include <math.h>

// Problem constants (match reference: B,C,W,H,D = 2,256,32,32,32)
#define Bc   2
#define Cc   256
#define Nn   32768            // W*H*D
#define CHc  128              // C/2
#define NPC  8                // channel chunks for mask-partial kernel
#define CPB  (Cc / NPC)       // 32 channels per block
#define NT   1024             // floats per n-tile (256 threads x float4)
#define NTILES (Nn / NT)      // 32
#define LN_EPS 1e-5f

// ---------------------------------------------------------------------------
// K1: mask partials. grid (NTILES, B, NPC), 256 thr. Each block accumulates
// wm-weighted channel sums for its 32-channel chunk over a 1024-float n-tile,
// for BOTH tensors. Writes (no atomics) to mp[tt][pc][b][n].
// ---------------------------------------------------------------------------
__global__ __launch_bounds__(256) void gc_k1_mask(
    const float* __restrict__ S, const float* __restrict__ T,
    const float* __restrict__ wms, const float* __restrict__ wmt,
    float* __restrict__ mp) {
  const int tile = blockIdx.x;
  const int b    = blockIdx.y;
  const int pc   = blockIdx.z;
  const int tid  = threadIdx.x;
  const int n0   = tile * NT + tid * 4;
  const int c0   = pc * CPB;

  const float* Sp = S + ((size_t)b * Cc + c0) * Nn + n0;
  const float* Tp = T + ((size_t)b * Cc + c0) * Nn + n0;

  float4 as = make_float4(0.f, 0.f, 0.f, 0.f);
  float4 at = make_float4(0.f, 0.f, 0.f, 0.f);

#pragma unroll 8
  for (int i = 0; i < CPB; ++i) {
    const float ws = wms[c0 + i];
    const float wt = wmt[c0 + i];
    const float4 s = *(const float4*)(Sp + (size_t)i * Nn);
    const float4 t = *(const float4*)(Tp + (size_t)i * Nn);
    as.x += ws * s.x; as.y += ws * s.y; as.z += ws * s.z; as.w += ws * s.w;
    at.x += wt * t.x; at.y += wt * t.y; at.z += wt * t.z; at.w += wt * t.w;
  }

  float* outS = mp + (((size_t)0 * NPC + pc) * Bc + b) * Nn + n0;
  float* outT = mp + (((size_t)1 * NPC + pc) * Bc + b) * Nn + n0;
  *(float4*)outS = as;
  *(float4*)outT = at;
}

// ---------------------------------------------------------------------------
// K2: softmax over n for each (tensor, b). grid (2,2), 256 thr.
// Sums the NPC partials + bias, then max / exp / normalize in-place into attn.
// Also zero-inits the sumsq accumulator (ws is poisoned each call).
// ---------------------------------------------------------------------------
__global__ __launch_bounds__(256) void gc_k2_softmax(
    const float* __restrict__ mp, const float* __restrict__ bms,
    const float* __restrict__ bmt, float* __restrict__ attn,
    float* __restrict__ sumsq) {
  const int tt  = blockIdx.x;
  const int b   = blockIdx.y;
  const int tid = threadIdx.x;
  if (tt == 0 && b == 0 && tid == 0) *sumsq = 0.f;

  const float bm = (tt ? bmt : bms)[0];
  float* at = attn + ((size_t)tt * Bc + b) * Nn;

  __shared__ float red[256];

  float mmax = -1e30f;
  for (int n = tid; n < Nn; n += 256) {
    float m = bm;
#pragma unroll
    for (int pc = 0; pc < NPC; ++pc)
      m += mp[(((size_t)tt * NPC + pc) * Bc + b) * Nn + n];
    at[n] = m;
    mmax = fmaxf(mmax, m);
  }
  red[tid] = mmax;
  __syncthreads();
  for (int s = 128; s > 0; s >>= 1) {
    if (tid < s) red[tid] = fmaxf(red[tid], red[tid + s]);
    __syncthreads();
  }
  const float M = red[0];
  __syncthreads();

  float lsum = 0.f;
  for (int n = tid; n < Nn; n += 256) {
    const float e = expf(at[n] - M);
    at[n] = e;
    lsum += e;
  }
  red[tid] = lsum;
  __syncthreads();
  for (int s = 128; s > 0; s >>= 1) {
    if (tid < s) red[tid] += red[tid + s];
    __syncthreads();
  }
  const float inv = 1.f / red[0];
  __syncthreads();

  for (int n = tid; n < Nn; n += 256) at[n] *= inv;
}

// ---------------------------------------------------------------------------
// K3: fused weighted pool + diff stats. grid (C, B), 256 thr — one block per
// (b,c) row. Computes ctx_s, ctx_t, rowsum(dS), and sumsq(dS^2) partial.
// Second full read of S,T — should hit Infinity Cache (128 MiB < 256 MiB L3).
// ---------------------------------------------------------------------------
__global__ __launch_bounds__(256) void gc_k3_pool(
    const float* __restrict__ S, const float* __restrict__ T,
    const float* __restrict__ attn, float* __restrict__ ctx,
    float* __restrict__ rowsum, float* __restrict__ sumsq) {
  const int c   = blockIdx.x;
  const int b   = blockIdx.y;
  const int tid = threadIdx.x;

  const float* Sp = S + ((size_t)b * Cc + c) * Nn;
  const float* Tp = T + ((size_t)b * Cc + c) * Nn;
  const float* a1 = attn + ((size_t)0 * Bc + b) * Nn;
  const float* a2 = attn + ((size_t)1 * Bc + b) * Nn;

  float cs = 0.f, ct = 0.f, rs = 0.f, sq = 0.f;
#pragma unroll 4
  for (int n = tid * 4; n < Nn; n += 1024) {
    const float4 s = *(const float4*)(Sp + n);
    const float4 t = *(const float4*)(Tp + n);
    const float4 w1 = *(const float4*)(a1 + n);
    const float4 w2 = *(const float4*)(a2 + n);
    cs += s.x * w1.x + s.y * w1.y + s.z * w1.z + s.w * w1.w;
    ct += t.x * w2.x + t.y * w2.y + t.z * w2.z + t.w * w2.w;
    const float dx = s.x - t.x, dy = s.y - t.y, dz = s.z - t.z, dw = s.w - t.w;
    rs += dx + dy + dz + dw;
    sq += dx * dx + dy * dy + dz * dz + dw * dw;
  }

  __shared__ float4 red4[256];
  red4[tid] = make_float4(cs, ct, rs, sq);
  __syncthreads();
  for (int s = 128; s > 0; s >>= 1) {
    if (tid < s) {
      red4[tid].x += red4[tid + s].x;
      red4[tid].y += red4[tid + s].y;
      red4[tid].z += red4[tid + s].z;
      red4[tid].w += red4[tid + s].w;
    }
    __syncthreads();
  }
  if (tid == 0) {
    const float4 r = red4[0];
    ctx[((size_t)0 * Bc + b) * Cc + c] = r.x;
    ctx[((size_t)1 * Bc + b) * Cc + c] = r.y;
    rowsum[(size_t)b * Cc + c] = r.z;
    atomicAdd(sumsq, r.w);
  }
}

// ---------------------------------------------------------------------------
// K4: tiny epilogue. 1 block, 256 thr. Both channel_add MLPs (conv1 + LN +
// ReLU + conv2) for S and T, then the closed-form final scalar.
// ---------------------------------------------------------------------------
__global__ __launch_bounds__(256) void gc_k4_final(
    const float* __restrict__ ctx, const float* __restrict__ rowsum,
    const float* __restrict__ sumsq,
    const float* __restrict__ w1s, const float* __restrict__ b1s,
    const float* __restrict__ gs,  const float* __restrict__ bes,
    const float* __restrict__ w2s, const float* __restrict__ b2s,
    const float* __restrict__ w1t, const float* __restrict__ b1t,
    const float* __restrict__ gt,  const float* __restrict__ bet,
    const float* __restrict__ w2t, const float* __restrict__ b2t,
    float* __restrict__ out) {
  const int tid = threadIdx.x;
  __shared__ float h[2][Bc][CHc];     // [tensor][b][j]
  __shared__ float addv[2][Bc][Cc];   // [tensor][b][c]
  __shared__ float stats[2][Bc][2];   // mu, rstd
  __shared__ float red[256];

  // stage 1: h = ctx @ w1.T + b1   (2*2*128 = 512 jobs)
  for (int job = tid; job < 2 * Bc * CHc; job += 256) {
    const int j  = job & (CHc - 1);
    const int b  = (job >> 7) & 1;
    const int tt = job >> 8;
    const float* w1 = tt ? w1t : w1s;
    const float* b1 = tt ? b1t : b1s;
    const float* cx = ctx + ((size_t)tt * Bc + b) * Cc;
    float acc = b1[j];
    for (int c = 0; c < Cc; ++c) acc += cx[c] * w1[j * Cc + c];
    h[tt][b][j] = acc;
  }
  __syncthreads();

  // stage 2: LN stats (4 serial threads; 128 elems each — trivial)
  if (tid < 4) {
    const int tt = tid >> 1, b = tid & 1;
    float mu = 0.f;
    for (int j = 0; j < CHc; ++j) mu += h[tt][b][j];
    mu /= (float)CHc;
    float var = 0.f;
    for (int j = 0; j < CHc; ++j) {
      const float d = h[tt][b][j] - mu;
      var += d * d;
    }
    var /= (float)CHc;
    stats[tt][b][0] = mu;
    stats[tt][b][1] = rsqrtf(var + LN_EPS);
  }
  __syncthreads();

  // normalize + affine + relu (in place: each job touches only its own elem)
  for (int job = tid; job < 2 * Bc * CHc; job += 256) {
    const int j  = job & (CHc - 1);
    const int b  = (job >> 7) & 1;
    const int tt = job >> 8;
    const float* g  = tt ? gt : gs;
    const float* be = tt ? bet : bes;
    float v = (h[tt][b][j] - stats[tt][b][0]) * stats[tt][b][1] * g[j] + be[j];
    h[tt][b][j] = v > 0.f ? v : 0.f;
  }
  __syncthreads();

  // stage 3: add = relu_h @ w2.T + b2   (2*2*256 = 1024 jobs)
  for (int job = tid; job < 2 * Bc * Cc; job += 256) {
    const int c  = job & (Cc - 1);
    const int b  = (job >> 8) & 1;
    const int tt = job >> 9;
    const float* w2 = tt ? w2t : w2s;
    const float* b2 = tt ? b2t : b2s;
    float acc = b2[c];
    for (int j = 0; j < CHc; ++j) acc += h[tt][b][j] * w2[c * CHc + j];
    addv[tt][b][c] = acc;
  }
  __syncthreads();

  // stage 4: out = (sumsq + sum_{b,c} [2*delta*rowsum + N*delta^2]) / B
  float part = 0.f;
  for (int job = tid; job < Bc * Cc; job += 256) {
    const int c = job & (Cc - 1);
    const int b = job >> 8;
    const float delta = addv[0][b][c] - addv[1][b][c];
    part += 2.f * delta * rowsum[(size_t)b * Cc + c] +
            (float)Nn * delta * delta;
  }
  red[tid] = part;
  __syncthreads();
  for (int s = 128; s > 0; s >>= 1) {
    if (tid < s) red[tid] += red[tid + s];
    __syncthreads();
  }
  if (tid == 0) out[0] = (red[0] + sumsq[0]) / (float)Bc;
}

// ---------------------------------------------------------------------------
extern "C" void kernel_launch(void* const* d_in, const int* in_sizes, int n_in,
                              void* d_out, int out_size, void* d_ws,
                              size_t ws_size, hipStream_t stream) {
  const float* S   = (const float*)d_in[0];
  const float* T   = (const float*)d_in[1];
  const float* wms = (const float*)d_in[2];
  const float* bms = (const float*)d_in[3];
  const float* wmt = (const float*)d_in[4];
  const float* bmt = (const float*)d_in[5];
  const float* w1s = (const float*)d_in[6];
  const float* b1s = (const float*)d_in[7];
  const float* gs  = (const float*)d_in[8];
  const float* bes = (const float*)d_in[9];
  const float* w2s = (const float*)d_in[10];
  const float* b2s = (const float*)d_in[11];
  const float* w1t = (const float*)d_in[12];
  const float* b1t = (const float*)d_in[13];
  const float* gt  = (const float*)d_in[14];
  const float* bet = (const float*)d_in[15];
  const float* w2t = (const float*)d_in[16];
  const float* b2t = (const float*)d_in[17];
  float* out = (float*)d_out;

  // ws layout (floats):
  float* ws     = (float*)d_ws;
  float* mp     = ws;                                  // 2*NPC*B*N = 1,048,576
  float* attn   = mp + (size_t)2 * NPC * Bc * Nn;      // 2*B*N = 131,072
  float* ctx    = attn + (size_t)2 * Bc * Nn;          // 2*B*C = 1024
  float* rowsum = ctx + (size_t)2 * Bc * Cc;           // B*C   = 512
  float* sumsq  = rowsum + (size_t)Bc * Cc;            // 1

  gc_k1_mask<<<dim3(NTILES, Bc, NPC), 256, 0, stream>>>(S, T, wms, wmt, mp);
  gc_k2_softmax<<<dim3(2, 2), 256, 0, stream>>>(mp, bms, bmt, attn, sumsq);
  gc_k3_pool<<<dim3(Cc, Bc), 256, 0, stream>>>(S, T, attn, ctx, rowsum, sumsq);
  gc_k4_final<<<1, 256, 0, stream>>>(ctx, rowsum, sumsq, w1s, b1s, gs, bes,
                                     w2s, b2s, w1t, b1t, gt, bet, w2t, b2t,
                                     out);
}

// Round 2
// 219.600 us; speedup vs baseline: 1.5321x; 1.5321x over previous
//
#include <hip/hip_runtime.h>
#include <math.h>
#include <limits.h>

// Problem constants (match reference: B,C,W,H,D = 2,256,32,32,32)
#define Bc   2
#define Cc   256
#define Nn   32768            // W*H*D
#define CHc  128              // C/2
#define NPC  8                // channel chunks for mask-partial kernel
#define CPB  (Cc / NPC)       // 32 channels per block
#define NT   1024             // floats per n-tile (256 threads x float4)
#define NTILES (Nn / NT)      // 32
#define LN_EPS 1e-5f

// Order-preserving int encoding of float for atomicMax (handles negatives).
__device__ __forceinline__ int enc_f(float f) {
  int i = __float_as_int(f);
  return i >= 0 ? i : (i ^ 0x7FFFFFFF);
}
__device__ __forceinline__ float dec_f(int k) {
  return __int_as_float(k >= 0 ? k : (k ^ 0x7FFFFFFF));
}

// ---------------------------------------------------------------------------
// K1: mask partials. grid (NTILES, B, NPC), 256 thr. Accumulates wm-weighted
// channel sums for a 32-channel chunk over a 1024-float n-tile, both tensors.
// Also (block 0) inits Mkey (encoded -inf) and sumsq=0 for later kernels.
// ---------------------------------------------------------------------------
__global__ __launch_bounds__(256) void gc_k1_mask(
    const float* __restrict__ S, const float* __restrict__ T,
    const float* __restrict__ wms, const float* __restrict__ wmt,
    float* __restrict__ mp, int* __restrict__ Mkey,
    float* __restrict__ sumsq) {
  const int tile = blockIdx.x;
  const int b    = blockIdx.y;
  const int pc   = blockIdx.z;
  const int tid  = threadIdx.x;

  if (tile == 0 && b == 0 && pc == 0) {
    if (tid < 4) Mkey[tid] = INT_MIN;
    if (tid == 4) *sumsq = 0.f;
  }

  const int n0 = tile * NT + tid * 4;
  const int c0 = pc * CPB;

  const float* Sp = S + ((size_t)b * Cc + c0) * Nn + n0;
  const float* Tp = T + ((size_t)b * Cc + c0) * Nn + n0;

  float4 as = make_float4(0.f, 0.f, 0.f, 0.f);
  float4 at = make_float4(0.f, 0.f, 0.f, 0.f);

#pragma unroll 8
  for (int i = 0; i < CPB; ++i) {
    const float ws = wms[c0 + i];
    const float wt = wmt[c0 + i];
    const float4 s = *(const float4*)(Sp + (size_t)i * Nn);
    const float4 t = *(const float4*)(Tp + (size_t)i * Nn);
    as.x += ws * s.x; as.y += ws * s.y; as.z += ws * s.z; as.w += ws * s.w;
    at.x += wt * t.x; at.y += wt * t.y; at.z += wt * t.z; at.w += wt * t.w;
  }

  float* outS = mp + (((size_t)0 * NPC + pc) * Bc + b) * Nn + n0;
  float* outT = mp + (((size_t)1 * NPC + pc) * Bc + b) * Nn + n0;
  *(float4*)outS = as;
  *(float4*)outT = at;
}

// ---------------------------------------------------------------------------
// K2a: combine 8 partials + bias -> mask[tt][b][n]; block-max -> atomicMax
// into Mkey[tt*2+b] (order-preserving int encoding). grid (NTILES, B, 2).
// ---------------------------------------------------------------------------
__global__ __launch_bounds__(256) void gc_k2a_combine(
    const float* __restrict__ mp, const float* __restrict__ bms,
    const float* __restrict__ bmt, float* __restrict__ mask,
    int* __restrict__ Mkey) {
  const int tile = blockIdx.x;
  const int b    = blockIdx.y;
  const int tt   = blockIdx.z;
  const int tid  = threadIdx.x;
  const int n0   = tile * NT + tid * 4;

  const float bm = (tt ? bmt : bms)[0];
  float4 m = make_float4(bm, bm, bm, bm);
#pragma unroll
  for (int pc = 0; pc < NPC; ++pc) {
    const float4 p =
        *(const float4*)(mp + (((size_t)tt * NPC + pc) * Bc + b) * Nn + n0);
    m.x += p.x; m.y += p.y; m.z += p.z; m.w += p.w;
  }
  *(float4*)(mask + ((size_t)tt * Bc + b) * Nn + n0) = m;

  float lmax = fmaxf(fmaxf(m.x, m.y), fmaxf(m.z, m.w));
  __shared__ float red[256];
  red[tid] = lmax;
  __syncthreads();
  for (int s = 128; s > 0; s >>= 1) {
    if (tid < s) red[tid] = fmaxf(red[tid], red[tid + s]);
    __syncthreads();
  }
  if (tid == 0) atomicMax(&Mkey[tt * Bc + b], enc_f(red[0]));
}

// ---------------------------------------------------------------------------
// K3: fused softmax-exp + weighted pool + diff stats. grid (C, B), 256 thr.
// Each block re-derives e=exp(mask-M) and its own denominator (identical
// across c — cheap VALU), so no normalized-attn pass is needed.
// ---------------------------------------------------------------------------
__global__ __launch_bounds__(256) void gc_k3_pool(
    const float* __restrict__ S, const float* __restrict__ T,
    const float* __restrict__ mask, const int* __restrict__ Mkey,
    float* __restrict__ ctx, float* __restrict__ rowsum,
    float* __restrict__ sumsq) {
  const int c   = blockIdx.x;
  const int b   = blockIdx.y;
  const int tid = threadIdx.x;

  const float M1 = dec_f(Mkey[0 * Bc + b]);
  const float M2 = dec_f(Mkey[1 * Bc + b]);

  const float* Sp = S + ((size_t)b * Cc + c) * Nn;
  const float* Tp = T + ((size_t)b * Cc + c) * Nn;
  const float* m1 = mask + ((size_t)0 * Bc + b) * Nn;
  const float* m2 = mask + ((size_t)1 * Bc + b) * Nn;

  float cs = 0.f, ct = 0.f, te1 = 0.f, te2 = 0.f, rs = 0.f, sq = 0.f;
  for (int n = tid * 4; n < Nn; n += 1024) {
    const float4 s = *(const float4*)(Sp + n);
    const float4 t = *(const float4*)(Tp + n);
    const float4 a = *(const float4*)(m1 + n);
    const float4 g = *(const float4*)(m2 + n);
    const float e1x = __expf(a.x - M1), e1y = __expf(a.y - M1),
                e1z = __expf(a.z - M1), e1w = __expf(a.w - M1);
    const float e2x = __expf(g.x - M2), e2y = __expf(g.y - M2),
                e2z = __expf(g.z - M2), e2w = __expf(g.w - M2);
    cs += s.x * e1x + s.y * e1y + s.z * e1z + s.w * e1w;
    ct += t.x * e2x + t.y * e2y + t.z * e2z + t.w * e2w;
    te1 += e1x + e1y + e1z + e1w;
    te2 += e2x + e2y + e2z + e2w;
    const float dx = s.x - t.x, dy = s.y - t.y, dz = s.z - t.z, dw = s.w - t.w;
    rs += dx + dy + dz + dw;
    sq += dx * dx + dy * dy + dz * dz + dw * dw;
  }

  __shared__ float red[6][256];
  red[0][tid] = cs;  red[1][tid] = ct;  red[2][tid] = te1;
  red[3][tid] = te2; red[4][tid] = rs;  red[5][tid] = sq;
  __syncthreads();
  for (int s = 128; s > 0; s >>= 1) {
    if (tid < s) {
#pragma unroll
      for (int k = 0; k < 6; ++k) red[k][tid] += red[k][tid + s];
    }
    __syncthreads();
  }
  if (tid == 0) {
    ctx[((size_t)0 * Bc + b) * Cc + c] = red[0][0] / red[2][0];
    ctx[((size_t)1 * Bc + b) * Cc + c] = red[1][0] / red[3][0];
    rowsum[(size_t)b * Cc + c] = red[4][0];
    atomicAdd(sumsq, red[5][0]);
  }
}

// ---------------------------------------------------------------------------
// K4a: channel_add MLP per (tt,b). grid 4, block 1024 (16 waves -> enough
// outstanding loads to stream 256 KiB of weights per block). float4 loads.
// ---------------------------------------------------------------------------
__global__ __launch_bounds__(1024) void gc_k4a_mlp(
    const float* __restrict__ ctx,
    const float* __restrict__ w1s, const float* __restrict__ b1s,
    const float* __restrict__ gs,  const float* __restrict__ bes,
    const float* __restrict__ w2s, const float* __restrict__ b2s,
    const float* __restrict__ w1t, const float* __restrict__ b1t,
    const float* __restrict__ gt,  const float* __restrict__ bet,
    const float* __restrict__ w2t, const float* __restrict__ b2t,
    float* __restrict__ addv) {
  const int tt  = blockIdx.x >> 1;
  const int b   = blockIdx.x & 1;
  const int tid = threadIdx.x;

  const float* w1 = tt ? w1t : w1s;
  const float* b1 = tt ? b1t : b1s;
  const float* g  = tt ? gt  : gs;
  const float* be = tt ? bet : bes;
  const float* w2 = tt ? w2t : w2s;
  const float* b2 = tt ? b2t : b2s;

  __shared__ float cxs[Cc];
  __shared__ float part[1024];
  __shared__ float hbuf[CHc];
  __shared__ float hr[CHc];
  __shared__ float2 red2[128];
  __shared__ float mu_s, rstd_s;

  if (tid < Cc) cxs[tid] = ctx[((size_t)tt * Bc + b) * Cc + tid];
  __syncthreads();

  // stage 1: h[j] = sum_c ctx[c]*w1[j][c] + b1[j]   (128 j x 8 segments)
  {
    const int j = tid >> 3, s = tid & 7;
    const float* wr = w1 + j * Cc + s * 32;
    const float4* cx4 = (const float4*)(cxs + s * 32);
    float acc = 0.f;
#pragma unroll
    for (int k = 0; k < 8; ++k) {
      const float4 w = *(const float4*)(wr + k * 4);
      const float4 x = cx4[k];
      acc += w.x * x.x + w.y * x.y + w.z * x.z + w.w * x.w;
    }
    part[tid] = acc;
  }
  __syncthreads();
  if (tid < CHc) {
    float h = b1[tid];
#pragma unroll
    for (int q = 0; q < 8; ++q) h += part[tid * 8 + q];
    hbuf[tid] = h;
  }
  __syncthreads();

  // LN stats over 128
  if (tid < CHc) {
    const float v = hbuf[tid];
    red2[tid] = make_float2(v, v * v);
  }
  __syncthreads();
  for (int s = 64; s > 0; s >>= 1) {
    if (tid < s) {
      red2[tid].x += red2[tid + s].x;
      red2[tid].y += red2[tid + s].y;
    }
    __syncthreads();
  }
  if (tid == 0) {
    const float mu = red2[0].x / (float)CHc;
    const float var = red2[0].y / (float)CHc - mu * mu;
    mu_s = mu;
    rstd_s = rsqrtf(var + LN_EPS);
  }
  __syncthreads();
  if (tid < CHc) {
    const float v = (hbuf[tid] - mu_s) * rstd_s * g[tid] + be[tid];
    hr[tid] = v > 0.f ? v : 0.f;
  }
  __syncthreads();

  // stage 3: addv[c] = sum_j hr[j]*w2[c][j] + b2[c]   (256 c x 4 segments)
  {
    const int c = tid >> 2, q = tid & 3;
    const float* wr = w2 + c * CHc + q * 32;
    const float4* h4 = (const float4*)(hr + q * 32);
    float acc = 0.f;
#pragma unroll
    for (int k = 0; k < 8; ++k) {
      const float4 w = *(const float4*)(wr + k * 4);
      const float4 x = h4[k];
      acc += w.x * x.x + w.y * x.y + w.z * x.z + w.w * x.w;
    }
    part[tid] = acc;
  }
  __syncthreads();
  if (tid < Cc) {
    float acc = b2[tid];
#pragma unroll
    for (int q = 0; q < 4; ++q) acc += part[tid * 4 + q];
    addv[((size_t)tt * Bc + b) * Cc + tid] = acc;
  }
}

// ---------------------------------------------------------------------------
// K4b: final scalar. 1 block, 256 thr.
// out = (sumsq + sum_{b,c} [2*delta*rowsum + N*delta^2]) / B
// ---------------------------------------------------------------------------
__global__ __launch_bounds__(256) void gc_k4b_final(
    const float* __restrict__ addv, const float* __restrict__ rowsum,
    const float* __restrict__ sumsq, float* __restrict__ out) {
  const int tid = threadIdx.x;
  __shared__ float red[256];
  float part = 0.f;
  for (int job = tid; job < Bc * Cc; job += 256) {
    const int c = job & (Cc - 1);
    const int b = job >> 8;
    const float delta = addv[((size_t)0 * Bc + b) * Cc + c] -
                        addv[((size_t)1 * Bc + b) * Cc + c];
    part += 2.f * delta * rowsum[(size_t)b * Cc + c] +
            (float)Nn * delta * delta;
  }
  red[tid] = part;
  __syncthreads();
  for (int s = 128; s > 0; s >>= 1) {
    if (tid < s) red[tid] += red[tid + s];
    __syncthreads();
  }
  if (tid == 0) out[0] = (red[0] + sumsq[0]) / (float)Bc;
}

// ---------------------------------------------------------------------------
extern "C" void kernel_launch(void* const* d_in, const int* in_sizes, int n_in,
                              void* d_out, int out_size, void* d_ws,
                              size_t ws_size, hipStream_t stream) {
  const float* S   = (const float*)d_in[0];
  const float* T   = (const float*)d_in[1];
  const float* wms = (const float*)d_in[2];
  const float* bms = (const float*)d_in[3];
  const float* wmt = (const float*)d_in[4];
  const float* bmt = (const float*)d_in[5];
  const float* w1s = (const float*)d_in[6];
  const float* b1s = (const float*)d_in[7];
  const float* gs  = (const float*)d_in[8];
  const float* bes = (const float*)d_in[9];
  const float* w2s = (const float*)d_in[10];
  const float* b2s = (const float*)d_in[11];
  const float* w1t = (const float*)d_in[12];
  const float* b1t = (const float*)d_in[13];
  const float* gt  = (const float*)d_in[14];
  const float* bet = (const float*)d_in[15];
  const float* w2t = (const float*)d_in[16];
  const float* b2t = (const float*)d_in[17];
  float* out = (float*)d_out;

  // ws layout (floats):
  float* ws     = (float*)d_ws;
  float* mp     = ws;                                  // 2*NPC*B*N = 1,048,576
  float* mask   = mp + (size_t)2 * NPC * Bc * Nn;      // 2*B*N = 131,072
  float* ctx    = mask + (size_t)2 * Bc * Nn;          // 2*B*C = 1024
  float* rowsum = ctx + (size_t)2 * Bc * Cc;           // B*C   = 512
  float* sumsq  = rowsum + (size_t)Bc * Cc;            // 1
  int*   Mkey   = (int*)(sumsq + 1);                   // 4 ints
  float* addv   = (float*)(Mkey + 4);                  // 2*B*C = 1024

  gc_k1_mask<<<dim3(NTILES, Bc, NPC), 256, 0, stream>>>(S, T, wms, wmt, mp,
                                                        Mkey, sumsq);
  gc_k2a_combine<<<dim3(NTILES, Bc, 2), 256, 0, stream>>>(mp, bms, bmt, mask,
                                                          Mkey);
  gc_k3_pool<<<dim3(Cc, Bc), 256, 0, stream>>>(S, T, mask, Mkey, ctx, rowsum,
                                               sumsq);
  gc_k4a_mlp<<<4, 1024, 0, stream>>>(ctx, w1s, b1s, gs, bes, w2s, b2s, w1t,
                                     b1t, gt, bet, w2t, b2t, addv);
  gc_k4b_final<<<1, 256, 0, stream>>>(addv, rowsum, sumsq, out);
}